// Round 4
// baseline (481.781 us; speedup 1.0000x reference)
//
#include <hip/hip_runtime.h>
#include <hip/hip_fp16.h>
#include <cstdint>
#include <cstddef>

typedef _Float16 f16x8  __attribute__((ext_vector_type(8)));
typedef _Float16 f16x4  __attribute__((ext_vector_type(4)));
typedef float    f32x4  __attribute__((ext_vector_type(4)));
typedef float    f32x16 __attribute__((ext_vector_type(16)));

#define GPTR(p) ((const __attribute__((address_space(1))) void*)(p))
#define SPTR(p) ((__attribute__((address_space(3))) void*)(p))

// ---------------------------------------------------------------------------
// Fused transpose+cast for up to 3 weight matrices (all R=2048 rows).
// z selects matrix; blocks with bx*32 >= C[z] early-out.
// ---------------------------------------------------------------------------
__global__ void transpose_cast3(const float* __restrict__ W0,
                                const float* __restrict__ W1,
                                const float* __restrict__ W2,
                                _Float16* __restrict__ T0,
                                _Float16* __restrict__ T1,
                                _Float16* __restrict__ T2,
                                int R, int C0, int C1, int C2) {
  const int z = blockIdx.z;
  const float* W = (z == 0) ? W0 : (z == 1) ? W1 : W2;
  _Float16*    T = (z == 0) ? T0 : (z == 1) ? T1 : T2;
  const int    C = (z == 0) ? C0 : (z == 1) ? C1 : C2;
  if (blockIdx.x * 32 >= C) return;

  __shared__ float tile[32][33];
  const int c  = blockIdx.x * 32 + threadIdx.x;
  const int r0 = blockIdx.y * 32;
  for (int i = threadIdx.y; i < 32; i += 8)
    tile[i][threadIdx.x] = W[(size_t)(r0 + i) * C + c];
  __syncthreads();
  const int out_c = r0 + threadIdx.x;
  const int oc0   = blockIdx.x * 32;
  for (int i = threadIdx.y; i < 32; i += 8)
    T[(size_t)(oc0 + i) * R + out_c] = (_Float16)tile[threadIdx.x][i];
}

// ---------------------------------------------------------------------------
// Fused flat cast fp32->fp16 for up to 3 equal-size (16M elem) matrices.
// Each block: 256 float4 = 1024 elems; 16384 blocks per matrix.
// ---------------------------------------------------------------------------
__global__ void cast3_f32_f16(const float* __restrict__ S0,
                              const float* __restrict__ S1,
                              const float* __restrict__ S2,
                              _Float16* __restrict__ D0,
                              _Float16* __restrict__ D1,
                              _Float16* __restrict__ D2) {
  const int idx = blockIdx.x >> 14;
  const float* src = (idx == 0) ? S0 : (idx == 1) ? S1 : S2;
  _Float16*    dst = (idx == 0) ? D0 : (idx == 1) ? D1 : D2;
  const size_t i = (size_t)(blockIdx.x & 16383) * 256 + threadIdx.x;
  const float4 v = ((const float4*)src)[i];
  f16x4 h;
  h[0] = (_Float16)v.x; h[1] = (_Float16)v.y;
  h[2] = (_Float16)v.z; h[3] = (_Float16)v.w;
  ((f16x4*)dst)[i] = h;
}

// ---------------------------------------------------------------------------
// GEMM: C(MxN) = A(MxK) @ Bt(NxK fp16)^T + bias, epilogue by MODE.
//   MODE 0: C = elu(acc + bias)           MODE 1: C = scale[row]*(acc + bias)
// Stacked-M via per-block B/bias select at row msplit.
// 128x128 tile, BK=64, 256 thr (4 waves 2x2), wave tile 64x64 as 2x2 subtiles
// of 32x32 using v_mfma_f32_32x32x16_f16 (129 matrix-cy/iter vs 155 for the
// 16x16x32 version; half the MFMA issue slots — m119: 2495 vs 2176 TF ceiling).
// LDS: tile row n, 16B k-chunk kc at slot n*8 + (kc ^ (n&7)); under the 32x32
// fragment map (row=lane&31, chunk=c*2+(lane>>5)) every slot-offset is hit by
// exactly 8 lanes -> ds_read_b128 at the 8-cycle minimum (conflict-free;
// SQ_LDS_BANK_CONFLICT==0 measured for this swizzle in rounds 2-3).
// ---------------------------------------------------------------------------
template <int MODE, bool AHALF, bool OUTHALF>
__global__ __launch_bounds__(256) void gemm2(
    const void* __restrict__ Av,
    const _Float16* __restrict__ Bt0, const _Float16* __restrict__ Bt1,
    const float* __restrict__ bias0, const float* __restrict__ bias1,
    int msplit, const float* __restrict__ scale,
    void* __restrict__ Cv, int K, int N) {
  constexpr int BK = 64;
  __shared__ __align__(16) _Float16 As[128 * BK];
  __shared__ __align__(16) _Float16 Bs[128 * BK];

  const int tid  = threadIdx.x;
  const int lane = tid & 63;
  const int wave = tid >> 6;
  const int l31  = lane & 31;
  const int khalf = lane >> 5;  // 0..1: k-parity group for 32x32 fragments
  const int wm   = wave >> 1;
  const int wn   = wave & 1;
  const int m0   = blockIdx.y * 128;
  const int n0   = blockIdx.x * 128;

  const _Float16* Bt = (m0 >= msplit) ? Bt1 : Bt0;
  const float* bias  = (m0 >= msplit) ? bias1 : bias0;

  // Per-lane staging source offsets. Slot s = wave*256 + t*64 + lane.
  size_t aoff[4], boff[4];
  int slot[4];
#pragma unroll
  for (int t = 0; t < 4; ++t) {
    const int s  = wave * 256 + t * 64 + lane;
    const int n  = s >> 3;
    const int kc = (s & 7) ^ (n & 7);
    aoff[t] = (size_t)(m0 + n) * K + kc * 8;
    boff[t] = (size_t)(n0 + n) * K + kc * 8;
    slot[t] = s;
  }

  f32x16 acc[2][2] = {};
  const _Float16* Ah = (const _Float16*)Av;
  const float*    Af = (const float*)Av;

  for (int k0 = 0; k0 < K; k0 += BK) {
    __syncthreads();
    if (AHALF) {
#pragma unroll
      for (int t = 0; t < 4; ++t)
        __builtin_amdgcn_global_load_lds(GPTR(Ah + aoff[t] + k0),
                                         SPTR(As + (wave * 256 + t * 64) * 8),
                                         16, 0, 0);
    } else {
#pragma unroll
      for (int t = 0; t < 4; ++t) {
        const float* ap = Af + aoff[t] + k0;
        const float4 v0 = *(const float4*)ap;
        const float4 v1 = *(const float4*)(ap + 4);
        f16x8 h;
        h[0] = (_Float16)v0.x; h[1] = (_Float16)v0.y;
        h[2] = (_Float16)v0.z; h[3] = (_Float16)v0.w;
        h[4] = (_Float16)v1.x; h[5] = (_Float16)v1.y;
        h[6] = (_Float16)v1.z; h[7] = (_Float16)v1.w;
        *(f16x8*)(As + (size_t)slot[t] * 8) = h;
      }
    }
#pragma unroll
    for (int t = 0; t < 4; ++t)
      __builtin_amdgcn_global_load_lds(GPTR(Bt + boff[t] + k0),
                                       SPTR(Bs + (wave * 256 + t * 64) * 8),
                                       16, 0, 0);
    __syncthreads();

    // 4 k-chunks of 16; A-frag: row=lane&31, k=(lane>>5)*8+j (j contiguous).
#pragma unroll
    for (int c = 0; c < 4; ++c) {
      const int kc = c * 2 + khalf;
      f16x8 af[2], bf[2];
#pragma unroll
      for (int t = 0; t < 2; ++t) {
        const int an = wm * 64 + t * 32 + l31;
        af[t] = *(const f16x8*)(As + (an * 8 + (kc ^ (an & 7))) * 8);
        const int bn = wn * 64 + t * 32 + l31;
        bf[t] = *(const f16x8*)(Bs + (bn * 8 + (kc ^ (bn & 7))) * 8);
      }
#pragma unroll
      for (int ti = 0; ti < 2; ++ti)
#pragma unroll
        for (int tj = 0; tj < 2; ++tj)
          acc[ti][tj] = __builtin_amdgcn_mfma_f32_32x32x16_f16(
              af[ti], bf[tj], acc[ti][tj], 0, 0, 0);
    }
  }

  // Epilogue: 32x32 C/D layout col=lane&31, row=(reg&3)+8*(reg>>2)+4*(lane>>5).
  float*    Cf = (float*)Cv;
  _Float16* Ch = (_Float16*)Cv;
#pragma unroll
  for (int ti = 0; ti < 2; ++ti) {
#pragma unroll
    for (int tj = 0; tj < 2; ++tj) {
      const int col = n0 + wn * 64 + tj * 32 + l31;
      const float b = bias[col];
#pragma unroll
      for (int reg = 0; reg < 16; ++reg) {
        const int row =
            m0 + wm * 64 + ti * 32 + (reg & 3) + 8 * (reg >> 2) + 4 * khalf;
        float v = acc[ti][tj][reg] + b;
        if (MODE == 0) v = v > 0.f ? v : (expf(v) - 1.f);  // ELU (no +1)
        else           v = v * scale[row];
        if (OUTHALF) Ch[(size_t)row * N + col] = (_Float16)v;
        else         Cf[(size_t)row * N + col] = v;
      }
    }
  }
}

// ---------------------------------------------------------------------------
// scale[b] = (Qf[b].Kf[b]) / (sum(Qf[b]) * sum(Kf[b]) + eps), F = 1024.
// ---------------------------------------------------------------------------
template <bool HALF>
__global__ void reduce_scale2(const void* __restrict__ Qf,
                              const void* __restrict__ Kf,
                              float* __restrict__ scale) {
  const int b = blockIdx.x;
  const int t = threadIdx.x;
  float q[4], k[4];
  if (HALF) {
    const f16x4 qh = ((const f16x4*)((const _Float16*)Qf + (size_t)b * 1024))[t];
    const f16x4 kh = ((const f16x4*)((const _Float16*)Kf + (size_t)b * 1024))[t];
#pragma unroll
    for (int i = 0; i < 4; ++i) { q[i] = (float)qh[i]; k[i] = (float)kh[i]; }
  } else {
    const float4 qv = ((const float4*)((const float*)Qf + (size_t)b * 1024))[t];
    const float4 kv = ((const float4*)((const float*)Kf + (size_t)b * 1024))[t];
    q[0] = qv.x; q[1] = qv.y; q[2] = qv.z; q[3] = qv.w;
    k[0] = kv.x; k[1] = kv.y; k[2] = kv.z; k[3] = kv.w;
  }
  float qk = q[0] * k[0] + q[1] * k[1] + q[2] * k[2] + q[3] * k[3];
  float sq = q[0] + q[1] + q[2] + q[3];
  float sk = k[0] + k[1] + k[2] + k[3];
#pragma unroll
  for (int off = 32; off > 0; off >>= 1) {
    qk += __shfl_down(qk, off, 64);
    sq += __shfl_down(sq, off, 64);
    sk += __shfl_down(sk, off, 64);
  }
  __shared__ float buf[3][4];
  const int lane = t & 63, wv = t >> 6;
  if (lane == 0) { buf[0][wv] = qk; buf[1][wv] = sq; buf[2][wv] = sk; }
  __syncthreads();
  if (t == 0) {
    const float QK = buf[0][0] + buf[0][1] + buf[0][2] + buf[0][3];
    const float SQ = buf[1][0] + buf[1][1] + buf[1][2] + buf[1][3];
    const float SK = buf[2][0] + buf[2][1] + buf[2][2] + buf[2][3];
    scale[b] = QK / (SQ * SK + 1e-6f);
  }
}

// ---------------------------------------------------------------------------
extern "C" void kernel_launch(void* const* d_in, const int* in_sizes, int n_in,
                              void* d_out, int out_size, void* d_ws,
                              size_t ws_size, hipStream_t stream) {
  const float* Q  = (const float*)d_in[0];
  const float* K_ = (const float*)d_in[1];
  const float* V  = (const float*)d_in[2];
  const float* Wq = (const float*)d_in[3];
  const float* bq = (const float*)d_in[4];
  const float* Wk = (const float*)d_in[5];
  const float* bk = (const float*)d_in[6];
  const float* Wv = (const float*)d_in[7];
  const float* bv = (const float*)d_in[8];
  float* out = (float*)d_out;

  const int B = 8192, D = 2048, F = 1024;
  const size_t MiB = 1u << 20;
  char* ws = (char*)d_ws;

  const size_t NEED_BIG  = 80 * MiB + 64 * 1024;  // no-alias layout, 5 dispatches
  const size_t NEED_FAST = 40 * MiB + 64 * 1024;  // aliased layout, 7 dispatches

  if (ws_size >= NEED_BIG) {
    // [0,4M) WqT | [4M,8M) WkT | [8M,16M) WvT | [16M,32M) QfH | [32M,48M) KfH
    // [48M,80M) Vh | [80M,+32K) scale.  Qh/Kh in d_out (exactly fills it).
    _Float16* WqT = (_Float16*)ws;
    _Float16* WkT = (_Float16*)(ws + 4 * MiB);
    _Float16* WvT = (_Float16*)(ws + 8 * MiB);
    _Float16* QfH = (_Float16*)(ws + 16 * MiB);
    _Float16* KfH = (_Float16*)(ws + 32 * MiB);
    _Float16* Vh  = (_Float16*)(ws + 48 * MiB);
    float* scale  = (float*)(ws + 80 * MiB);
    _Float16* Qh = (_Float16*)d_out;
    _Float16* Kh = (_Float16*)d_out + (size_t)B * D;

    transpose_cast3<<<dim3(64, 64, 3), dim3(32, 8), 0, stream>>>(
        Wq, Wk, Wv, WqT, WkT, WvT, D, F, F, D);
    cast3_f32_f16<<<3 * 16384, 256, 0, stream>>>(Q, K_, V, Qh, Kh, Vh);

    gemm2<0, true, true><<<dim3(F / 128, (2 * B) / 128), 256, 0, stream>>>(
        Qh, WqT, WkT, bq, bk, B, nullptr, QfH, D, F);
    reduce_scale2<true><<<B, 256, 0, stream>>>(QfH, KfH, scale);
    gemm2<1, true, false><<<dim3(D / 128, B / 128), 256, 0, stream>>>(
        Vh, WvT, WvT, bv, bv, 1 << 30, scale, out, D, D);
  } else if (ws_size >= NEED_FAST) {
    // Aliased: WvT reuses WqT/WkT region; Vh reuses QfH/KfH region.
    _Float16* WqT = (_Float16*)ws;
    _Float16* WkT = (_Float16*)(ws + 4 * MiB);
    _Float16* WvT = (_Float16*)ws;
    _Float16* QfH = (_Float16*)(ws + 8 * MiB);
    _Float16* KfH = (_Float16*)(ws + 24 * MiB);
    _Float16* Vh  = (_Float16*)(ws + 8 * MiB);
    float* scale  = (float*)(ws + 40 * MiB);
    _Float16* Qh = (_Float16*)d_out;
    _Float16* Kh = (_Float16*)d_out + (size_t)B * D;

    transpose_cast3<<<dim3(32, 64, 2), dim3(32, 8), 0, stream>>>(
        Wq, Wk, Wk, WqT, WkT, WkT, D, F, F, F);
    cast3_f32_f16<<<2 * 16384, 256, 0, stream>>>(Q, K_, K_, Qh, Kh, Kh);

    gemm2<0, true, true><<<dim3(F / 128, (2 * B) / 128), 256, 0, stream>>>(
        Qh, WqT, WkT, bq, bk, B, nullptr, QfH, D, F);
    reduce_scale2<true><<<B, 256, 0, stream>>>(QfH, KfH, scale);

    cast3_f32_f16<<<16384, 256, 0, stream>>>(V, V, V, Vh, Vh, Vh);
    transpose_cast3<<<dim3(64, 64, 1), dim3(32, 8), 0, stream>>>(
        Wv, Wv, Wv, WvT, WvT, WvT, D, D, D, D);
    gemm2<1, true, false><<<dim3(D / 128, B / 128), 256, 0, stream>>>(
        Vh, WvT, WvT, bv, bv, 1 << 30, scale, out, D, D);
  } else {
    // Fallback: fp32 A staging in-kernel, Qf/Kf fp32 in d_out.
    _Float16* WqT = (_Float16*)ws;
    _Float16* WkT = (_Float16*)(ws + 4 * MiB);
    _Float16* WvT = (_Float16*)(ws + 8 * MiB);
    float* scale  = (float*)(ws + 16 * MiB);
    float* Qf = out;
    float* Kf = out + (size_t)B * F;

    transpose_cast3<<<dim3(64, 64, 3), dim3(32, 8), 0, stream>>>(
        Wq, Wk, Wv, WqT, WkT, WvT, D, F, F, D);
    gemm2<0, false, false><<<dim3(F / 128, B / 128), 256, 0, stream>>>(
        Q, WqT, WqT, bq, bq, 1 << 30, nullptr, Qf, D, F);
    gemm2<0, false, false><<<dim3(F / 128, B / 128), 256, 0, stream>>>(
        K_, WkT, WkT, bk, bk, 1 << 30, nullptr, Kf, D, F);
    reduce_scale2<false><<<B, 256, 0, stream>>>(Qf, Kf, scale);
    gemm2<1, false, false><<<dim3(D / 128, B / 128), 256, 0, stream>>>(
        V, WvT, WvT, bv, bv, 1 << 30, scale, out, D, D);
  }
}